// Round 6
// baseline (6617.536 us; speedup 1.0000x reference)
//
#include <hip/hip_runtime.h>
#include <stdint.h>

typedef unsigned int u32;
typedef unsigned short u16;
typedef __attribute__((ext_vector_type(4))) float f32x4;
typedef __attribute__((ext_vector_type(4))) float f32x4v;
typedef __attribute__((ext_vector_type(8))) short bf16x8;

#define T_LEN 100
#define S_LEN 400
#define NB 16
#define HD 512
#define CTXD 1024
#define VOC 50000
#define K4H 2048
#define M_ALL 1600

static __device__ __forceinline__ float bf2f(u16 v) {
  union { u32 u; float f; } c; c.u = ((u32)v) << 16; return c.f;
}
static __device__ __forceinline__ u16 f2bf(float f) {
  union { float f; u32 u; } c; c.f = f;
  return (u16)((c.u + 0x7fffu + ((c.u >> 16) & 1u)) >> 16);
}
static __device__ __forceinline__ u32 pack2(float a, float b) {
  return (u32)f2bf(a) | ((u32)f2bf(b) << 16);
}
static __device__ __forceinline__ uint4 pack8(float4 a, float4 b) {
  return make_uint4(pack2(a.x, a.y), pack2(a.z, a.w), pack2(b.x, b.y), pack2(b.z, b.w));
}
static __device__ __forceinline__ uint4 pack8v(f32x4v a, f32x4v b) {
  return make_uint4(pack2(a.x, a.y), pack2(a.z, a.w), pack2(b.x, b.y), pack2(b.z, b.w));
}
static __device__ __forceinline__ float sigm(float x) { return 1.f / (1.f + __expf(-x)); }
static __device__ __forceinline__ float tanh_(float x) {
  float e = __expf(2.f * x);
  return 1.f - 2.f / (e + 1.f);
}

__global__ void sentinel_kernel(float* out, float v) {
  if (threadIdx.x < NB) out[threadIdx.x] = v;
}

// ---------------- fused cast kernel: 8 f32->bf16 segments + fill_feat_y ----------------
struct CastArgs {
  const float* src[9];
  u16* dst[9];
  u32 cum[10];  // cumulative n8 (groups of 8 elements)
};

__global__ __launch_bounds__(256) void cast_all(CastArgs A) {
  u32 i = blockIdx.x * 256 + threadIdx.x;
  if (i >= A.cum[9]) return;
  int seg = 0;
  while (i >= A.cum[seg + 1]) seg++;
  u32 li = i - A.cum[seg];
  const float* s = A.src[seg];
  f32x4v a = __builtin_nontemporal_load((const f32x4v*)&s[li * 8]);
  f32x4v b = __builtin_nontemporal_load((const f32x4v*)&s[li * 8 + 4]);
  if (seg < 8) {
    *(uint4*)&A.dst[seg][li * 8] = pack8v(a, b);
  } else {  // y_emb -> feat[:, 1536:2048]
    u32 m = li >> 6, k8 = (li & 63) << 3;
    *(uint4*)&A.dst[8][(size_t)m * K4H + 1536 + k8] = pack8v(a, b);
  }
}

// ---------------- generic bf16 MFMA GEMM: C[M,N] = A[M,K] * B[N,K]^T + bias ----------------
template <int MODE>
__global__ __launch_bounds__(256) void gemm_bf16(const u16* __restrict__ A,
                                                 const u16* __restrict__ Bw,
                                                 void* __restrict__ out,
                                                 const float* __restrict__ bias1,
                                                 const float* __restrict__ bias2,
                                                 int M, int N, int K) {
  __shared__ u16 As[64][40];
  __shared__ u16 Bs[64][40];
  int nb = N / 64;
  int m0 = (blockIdx.x / nb) * 64;
  int n0 = (blockIdx.x % nb) * 64;
  int tid = threadIdx.x;
  int lane = tid & 63;
  int w = tid >> 6;
  int wm = (w >> 1) * 32, wn = (w & 1) * 32;
  f32x4 acc[2][2] = {};
  int arow = tid >> 2, achk = (tid & 3) * 8;
  for (int k0 = 0; k0 < K; k0 += 32) {
    __syncthreads();
    *(uint4*)&As[arow][achk] = *(const uint4*)&A[(size_t)(m0 + arow) * K + k0 + achk];
    *(uint4*)&Bs[arow][achk] = *(const uint4*)&Bw[(size_t)(n0 + arow) * K + k0 + achk];
    __syncthreads();
    int r = lane & 15, kg = lane >> 4;
    bf16x8 a0 = *(const bf16x8*)&As[wm + r][kg * 8];
    bf16x8 a1 = *(const bf16x8*)&As[wm + 16 + r][kg * 8];
    bf16x8 b0 = *(const bf16x8*)&Bs[wn + r][kg * 8];
    bf16x8 b1 = *(const bf16x8*)&Bs[wn + 16 + r][kg * 8];
    acc[0][0] = __builtin_amdgcn_mfma_f32_16x16x32_bf16(a0, b0, acc[0][0], 0, 0, 0);
    acc[0][1] = __builtin_amdgcn_mfma_f32_16x16x32_bf16(a0, b1, acc[0][1], 0, 0, 0);
    acc[1][0] = __builtin_amdgcn_mfma_f32_16x16x32_bf16(a1, b0, acc[1][0], 0, 0, 0);
    acc[1][1] = __builtin_amdgcn_mfma_f32_16x16x32_bf16(a1, b1, acc[1][1], 0, 0, 0);
  }
  int col = lane & 15, rg = lane >> 4;
#pragma unroll
  for (int fi = 0; fi < 2; fi++)
#pragma unroll
    for (int fj = 0; fj < 2; fj++)
#pragma unroll
      for (int r = 0; r < 4; r++) {
        int m = m0 + wm + fi * 16 + rg * 4 + r;
        int n = n0 + wn + fj * 16 + col;
        float v = acc[fi][fj][r] + bias1[n];
        if constexpr (MODE == 1) {
          v += bias2[n];
          ((float*)out)[(size_t)m * N + n] = v;
        } else {
          ((u16*)out)[(size_t)m * N + n] = f2bf(v);
        }
      }
}

// ============ per-step kernels (3 launches per step; stream order = sync) ============

// K1Q: LSTM1 + q-partials. grid 16 blocks (j-slice of 32), 256 thr.
__global__ __launch_bounds__(256) void k1q_lstm(const u16* __restrict__ Whh,
                                                const u16* __restrict__ Wcomb,
                                                const float* __restrict__ xW,
                                                const float* __restrict__ ym,
                                                const float* __restrict__ h,
                                                const float* __restrict__ c,
                                                float* __restrict__ h1,
                                                float* __restrict__ c1,
                                                float* __restrict__ qpart, int ts) {
  __shared__ u16 Al[16 * 520];
  __shared__ float gb[4][16][32];
  __shared__ u16 h1c1[16 * 72];
  const int tid = threadIdx.x;
#pragma unroll
  for (int i = 0; i < 4; i++) {
    int idx = i * 256 + tid;
    int b = idx >> 6, k8 = (idx & 63) << 3;
    float4 a = *(const float4*)&h[b * 512 + k8];
    float4 bv = *(const float4*)&h[b * 512 + k8 + 4];
    *(uint4*)&Al[b * 520 + k8] = pack8(a, bv);
  }
  __syncthreads();
  const int lane = tid & 63, w = tid >> 6;  // w = gate in phase 1
  const int r16 = lane & 15, kg = lane >> 4;
  const int j0 = blockIdx.x * 32;
  {
    f32x4 acc0 = {}, acc1 = {};
    const size_t row0 = (size_t)(w * 512 + j0 + r16) * 512;
    const size_t row1 = (size_t)(w * 512 + j0 + 16 + r16) * 512;
#pragma unroll
    for (int ks = 0; ks < 16; ks++) {
      bf16x8 a = *(const bf16x8*)&Al[r16 * 520 + ks * 32 + kg * 8];
      bf16x8 b0 = *(const bf16x8*)&Whh[row0 + ks * 32 + kg * 8];
      bf16x8 b1 = *(const bf16x8*)&Whh[row1 + ks * 32 + kg * 8];
      acc0 = __builtin_amdgcn_mfma_f32_16x16x32_bf16(a, b0, acc0, 0, 0, 0);
      acc1 = __builtin_amdgcn_mfma_f32_16x16x32_bf16(a, b1, acc1, 0, 0, 0);
    }
#pragma unroll
    for (int r = 0; r < 4; r++) {
      gb[w][kg * 4 + r][r16] = acc0[r];
      gb[w][kg * 4 + r][16 + r16] = acc1[r];
    }
  }
  __syncthreads();
#pragma unroll
  for (int i = 0; i < 2; i++) {
    int idx = i * 256 + tid;
    int b = idx >> 5, j = idx & 31;
    int n = j0 + j;
    const float* xw = &xW[(size_t)(ts * NB + b) * K4H];
    float gi = gb[0][b][j] + xw[n];
    float gf = gb[1][b][j] + xw[512 + n];
    float gg = gb[2][b][j] + xw[1024 + n];
    float go = gb[3][b][j] + xw[1536 + n];
    float ymv = ym[ts * NB + b];
    float c_old = c[b * 512 + n], h_old = h[b * 512 + n];
    float c1v = sigm(gf) * c_old + sigm(gi) * tanh_(gg);
    float h1v = sigm(go) * tanh_(c1v);
    h1v = ymv * h1v + (1.f - ymv) * h_old;
    c1v = ymv * c1v + (1.f - ymv) * c_old;
    h1[b * 512 + n] = h1v;
    c1[b * 512 + n] = c1v;
    h1c1[b * 72 + j] = f2bf(h1v);
    h1c1[b * 72 + 32 + j] = f2bf(c1v);
  }
  __syncthreads();
  // phase 2: qpart[blk][b][n] = h1_slice @ Wcomb[:, j0:j0+32]^T + c1_slice @ Wcomb[:, 512+j0:...]^T
  {
    bf16x8 a0 = *(const bf16x8*)&h1c1[r16 * 72 + kg * 8];
    bf16x8 a1 = *(const bf16x8*)&h1c1[r16 * 72 + 32 + kg * 8];
    float* qp = qpart + blockIdx.x * 16384;
    for (int nt = w; nt < 64; nt += 4) {
      int n = nt * 16 + r16;
      bf16x8 b0 = *(const bf16x8*)&Wcomb[(size_t)n * 1024 + j0 + kg * 8];
      bf16x8 b1 = *(const bf16x8*)&Wcomb[(size_t)n * 1024 + 512 + j0 + kg * 8];
      f32x4 acc = {};
      acc = __builtin_amdgcn_mfma_f32_16x16x32_bf16(a0, b0, acc, 0, 0, 0);
      acc = __builtin_amdgcn_mfma_f32_16x16x32_bf16(a1, b1, acc, 0, 0, 0);
#pragma unroll
      for (int r = 0; r < 4; r++) qp[(kg * 4 + r) * 1024 + nt * 16 + r16] = acc[r];
    }
  }
}

// K3: attention. grid 128 = 8 s-ranges x 16 batches, 256 thr.
__global__ __launch_bounds__(256) void k3_attn(const u16* __restrict__ pctx,
                                               const u16* __restrict__ ctxb,
                                               const float* __restrict__ qpart,
                                               const float* __restrict__ xmask,
                                               const float* __restrict__ uatt,
                                               float* __restrict__ attnum,
                                               float* __restrict__ attden, int par) {
  __shared__ float q_l[1024], ua_l[1024], p_l[56], xm_l[56];
  const int tid = threadIdx.x;
  const int b = blockIdx.x & 15;
  const int s0 = (blockIdx.x >> 4) * 50;
  {
    float4 qs = {0.f, 0.f, 0.f, 0.f};
#pragma unroll
    for (int s_ = 0; s_ < 16; s_++) {
      float4 v = *(const float4*)&qpart[s_ * 16384 + b * 1024 + tid * 4];
      qs.x += v.x; qs.y += v.y; qs.z += v.z; qs.w += v.w;
    }
    *(float4*)&q_l[tid * 4] = qs;
  }
  *(float4*)&ua_l[tid * 4] = *(const float4*)&uatt[tid * 4];
  if (tid < 50) xm_l[tid] = xmask[(s0 + tid) * NB + b];
  __syncthreads();
  const int w = tid >> 6, lane = tid & 63;
  for (int i = w; i < 50; i += 4) {
    const u16* prow = &pctx[((size_t)(s0 + i) * NB + b) * CTXD + lane * 16];
    float s = 0.f;
#pragma unroll
    for (int half = 0; half < 2; half++) {
      bf16x8 pv = *(const bf16x8*)&prow[half * 8];
#pragma unroll
      for (int e = 0; e < 8; e++) {
        int cc = lane * 16 + half * 8 + e;
        s += tanh_(bf2f((u16)pv[e]) + q_l[cc]) * ua_l[cc];
      }
    }
#pragma unroll
    for (int off = 1; off < 64; off <<= 1) s += __shfl_xor(s, off);
    if (lane == 0) {
      float xm = xm_l[i];
      p_l[i] = __expf(s * xm) * xm;
    }
  }
  __syncthreads();
  const int c4 = tid << 2;
  float n0 = 0, n1 = 0, n2 = 0, n3 = 0;
  for (int i = 0; i < 50; i++) {
    float pv = p_l[i];
    uint2 ld = *(const uint2*)&ctxb[((size_t)(s0 + i) * NB + b) * CTXD + c4];
    n0 += pv * bf2f((u16)(ld.x & 0xffff));
    n1 += pv * bf2f((u16)(ld.x >> 16));
    n2 += pv * bf2f((u16)(ld.y & 0xffff));
    n3 += pv * bf2f((u16)(ld.y >> 16));
  }
  float* dst = &attnum[par * 16384 + b * 1024 + c4];
  atomicAdd(dst + 0, n0);
  atomicAdd(dst + 1, n1);
  atomicAdd(dst + 2, n2);
  atomicAdd(dst + 3, n3);
  if (tid == 0) {
    float d = 0.f;
    for (int i = 0; i < 50; i++) d += p_l[i];
    atomicAdd(&attden[par * NB + b], d);
  }
}

// K4: gates2 + h2/c2 + feat writes + zero other-parity att slot. grid 32, 256 thr.
__global__ __launch_bounds__(256) void k4_gate2(const u16* __restrict__ Uxw,
                                                const u16* __restrict__ Wxw,
                                                const float* __restrict__ bx,
                                                float* __restrict__ attnum,
                                                float* __restrict__ attden,
                                                const float* __restrict__ h1,
                                                const float* __restrict__ c1,
                                                const float* __restrict__ ym,
                                                float* __restrict__ h,
                                                float* __restrict__ c,
                                                u16* __restrict__ feat, int ts, int par) {
  __shared__ u16 Al[16 * 1544];
  __shared__ float gb[4][16][16];
  const int tid = threadIdx.x;
#pragma unroll
  for (int i = 0; i < 4; i++) {
    int idx = i * 256 + tid;
    int b = idx >> 6, k8 = (idx & 63) << 3;
    float4 a = *(const float4*)&h1[b * 512 + k8];
    float4 bv = *(const float4*)&h1[b * 512 + k8 + 4];
    *(uint4*)&Al[b * 1544 + k8] = pack8(a, bv);
  }
#pragma unroll
  for (int i = 0; i < 8; i++) {
    int idx = i * 256 + tid;
    int b = idx >> 7, c8 = (idx & 127) << 3;
    float rd = 1.f / attden[par * NB + b];
    const float* src = &attnum[par * 16384 + b * 1024 + c8];
    float4 a = *(const float4*)&src[0];
    float4 bv = *(const float4*)&src[4];
    a.x *= rd; a.y *= rd; a.z *= rd; a.w *= rd;
    bv.x *= rd; bv.y *= rd; bv.z *= rd; bv.w *= rd;
    *(uint4*)&Al[b * 1544 + 512 + c8] = pack8(a, bv);
  }
  __syncthreads();
  if (blockIdx.x < 16) {
#pragma unroll
    for (int r = 0; r < 4; r++) {
      int cc = r * 256 + tid;
      feat[(size_t)(ts * NB + blockIdx.x) * K4H + 512 + cc] = Al[blockIdx.x * 1544 + 512 + cc];
    }
  }
  const int lane = tid & 63, w = tid >> 6;  // w = gate (order i,f,o,c)
  const int r16 = lane & 15, kg = lane >> 4;
  const int j0 = blockIdx.x * 16;
  f32x4 acc = {};
  const size_t rowU = (size_t)(w * 512 + j0 + r16) * 512;
  const size_t rowW = (size_t)(w * 512 + j0 + r16) * 1024;
#pragma unroll
  for (int ks = 0; ks < 16; ks++) {
    bf16x8 a = *(const bf16x8*)&Al[r16 * 1544 + ks * 32 + kg * 8];
    bf16x8 b0 = *(const bf16x8*)&Uxw[rowU + ks * 32 + kg * 8];
    acc = __builtin_amdgcn_mfma_f32_16x16x32_bf16(a, b0, acc, 0, 0, 0);
  }
#pragma unroll
  for (int ks = 16; ks < 48; ks++) {
    bf16x8 a = *(const bf16x8*)&Al[r16 * 1544 + ks * 32 + kg * 8];
    bf16x8 b0 = *(const bf16x8*)&Wxw[rowW + (ks - 16) * 32 + kg * 8];
    acc = __builtin_amdgcn_mfma_f32_16x16x32_bf16(a, b0, acc, 0, 0, 0);
  }
#pragma unroll
  for (int r = 0; r < 4; r++) gb[w][kg * 4 + r][r16] = acc[r];
  __syncthreads();
  {
    int b = tid >> 4, j = tid & 15;
    int n = j0 + j;
    float xi = gb[0][b][j] + bx[n];
    float xf = gb[1][b][j] + bx[512 + n];
    float xo = gb[2][b][j] + bx[1024 + n];
    float xc = gb[3][b][j] + bx[1536 + n];
    float ymv = ym[ts * NB + b];
    float c1v = c1[b * 512 + n], h1v = h1[b * 512 + n];
    float c2 = sigm(xf) * c1v + sigm(xi) * tanh_(xc);
    float h2 = sigm(xo) * tanh_(c2);
    c2 = ymv * c2 + (1.f - ymv) * c1v;
    h2 = ymv * h2 + (1.f - ymv) * h1v;
    h[b * 512 + n] = h2;
    c[b * 512 + n] = c2;
    feat[(size_t)(ts * NB + b) * K4H + n] = f2bf(h2);
  }
  attnum[(par ^ 1) * 16384 + blockIdx.x * 512 + tid] = 0.f;
  attnum[(par ^ 1) * 16384 + blockIdx.x * 512 + 256 + tid] = 0.f;
  if (blockIdx.x == 0 && tid < NB) attden[(par ^ 1) * NB + tid] = 0.f;
}

// ---------------- fused vocab GEMM + sum(exp) ----------------
__global__ __launch_bounds__(512, 1) void lse_gemm(const u16* __restrict__ feat,
                                                   const float* __restrict__ Wp,
                                                   const float* __restrict__ bp,
                                                   float* __restrict__ lse) {
  extern __shared__ char smem[];
  u16* Bl = (u16*)smem;  // [32][2056] bf16
  const int tid = threadIdx.x;
  const int n0 = blockIdx.x * 32;
  for (int n = 0; n < 32; n++) {
    int gn = n0 + n;
    f32x4v f = {0.f, 0.f, 0.f, 0.f};
    if (gn < VOC)
      f = __builtin_nontemporal_load((const f32x4v*)&Wp[(size_t)gn * K4H + tid * 4]);
    uint2 t;
    t.x = pack2(f.x, f.y);
    t.y = pack2(f.z, f.w);
    *(uint2*)&Bl[n * 2056 + tid * 4] = t;
  }
  __syncthreads();
  const int w = tid >> 6, lane = tid & 63;
  const int r16 = lane & 15, kg = lane >> 4;
  int nf0 = n0 + r16, nf1 = n0 + 16 + r16;
  bool v0 = nf0 < VOC, v1 = nf1 < VOC;
  float bp0 = v0 ? bp[nf0] : 0.f;
  float bp1 = v1 ? bp[nf1] : 0.f;
  for (int qq = w; qq < 25; qq += 8) {
    int mrow = qq * 64;
    f32x4 acc[4][2] = {};
    for (int ks = 0; ks < 64; ks++) {
      bf16x8 b0 = *(const bf16x8*)&Bl[r16 * 2056 + ks * 32 + kg * 8];
      bf16x8 b1 = *(const bf16x8*)&Bl[(r16 + 16) * 2056 + ks * 32 + kg * 8];
#pragma unroll
      for (int s = 0; s < 4; s++) {
        bf16x8 a = *(const bf16x8*)&feat[(size_t)(mrow + s * 16 + r16) * K4H + ks * 32 + kg * 8];
        acc[s][0] = __builtin_amdgcn_mfma_f32_16x16x32_bf16(a, b0, acc[s][0], 0, 0, 0);
        acc[s][1] = __builtin_amdgcn_mfma_f32_16x16x32_bf16(a, b1, acc[s][1], 0, 0, 0);
      }
    }
#pragma unroll
    for (int s = 0; s < 4; s++) {
#pragma unroll
      for (int r = 0; r < 4; r++) {
        float e = (v0 ? __expf(acc[s][0][r] + bp0) : 0.f) +
                  (v1 ? __expf(acc[s][1][r] + bp1) : 0.f);
        e += __shfl_xor(e, 1);
        e += __shfl_xor(e, 2);
        e += __shfl_xor(e, 4);
        e += __shfl_xor(e, 8);
        if (r16 == 0) atomicAdd(&lse[mrow + s * 16 + kg * 4 + r], e);
      }
    }
  }
}

// ---------------- target logit + final cost ----------------
__global__ __launch_bounds__(256) void target_logit(const u16* __restrict__ feat,
                                                    const float* __restrict__ Wp,
                                                    const float* __restrict__ bp,
                                                    const int* __restrict__ yidx,
                                                    float* __restrict__ tlog) {
  int gw = (blockIdx.x * 256 + threadIdx.x) >> 6;
  int lane = threadIdx.x & 63;
  if (gw >= M_ALL) return;
  int yi = yidx[gw];
  const float* wrow = Wp + (size_t)yi * K4H;
  const u16* frow = feat + (size_t)gw * K4H;
  float s = 0.f;
#pragma unroll
  for (int i = 0; i < 4; i++) {
    int k = i * 512 + lane * 8;
    bf16x8 fv = *(const bf16x8*)&frow[k];
    f32x4v w0 = __builtin_nontemporal_load((const f32x4v*)&wrow[k]);
    f32x4v w1 = __builtin_nontemporal_load((const f32x4v*)&wrow[k + 4]);
    s += bf2f((u16)fv[0]) * w0.x + bf2f((u16)fv[1]) * w0.y + bf2f((u16)fv[2]) * w0.z +
         bf2f((u16)fv[3]) * w0.w + bf2f((u16)fv[4]) * w1.x + bf2f((u16)fv[5]) * w1.y +
         bf2f((u16)fv[6]) * w1.z + bf2f((u16)fv[7]) * w1.w;
  }
#pragma unroll
  for (int off = 1; off < 64; off <<= 1) s += __shfl_xor(s, off);
  if (lane == 0) tlog[gw] = s + bp[yi];
}

__global__ void finalize(const float* __restrict__ lse, const float* __restrict__ tlog,
                         const float* __restrict__ ymask, float* __restrict__ out) {
  int b = threadIdx.x;
  if (b < NB) {
    float sc = 0.f, sm = 0.f;
    for (int t = 0; t < T_LEN; t++) {
      int m = t * NB + b;
      float ym = ymask[m];
      sc += (logf(lse[m]) - tlog[m]) * ym;
      sm += ym;
    }
    out[b] = sc / sm;
  }
}

// ---------------- host launcher ----------------
extern "C" void kernel_launch(void* const* d_in, const int* in_sizes, int n_in,
                              void* d_out, int out_size, void* d_ws, size_t ws_size,
                              hipStream_t stream) {
  const float* y_emb = (const float*)d_in[0];
  const float* context = (const float*)d_in[1];
  const float* init_h = (const float*)d_in[2];
  const float* init_c = (const float*)d_in[3];
  const float* x_mask = (const float*)d_in[4];
  const float* y_mask = (const float*)d_in[5];
  const int* y_idx = (const int*)d_in[6];
  const float* W_ih = (const float*)d_in[7];
  const float* W_hh = (const float*)d_in[8];
  const float* b_ih = (const float*)d_in[9];
  const float* b_hh = (const float*)d_in[10];
  const float* Wx = (const float*)d_in[11];
  const float* Ux = (const float*)d_in[12];
  const float* bx = (const float*)d_in[13];
  const float* Wc_att = (const float*)d_in[14];
  const float* b_att = (const float*)d_in[15];
  const float* W_comb = (const float*)d_in[16];
  const float* U_att = (const float*)d_in[17];
  const float* Wp = (const float*)d_in[18];
  const float* bp = (const float*)d_in[19];

  if (ws_size < 63000000ULL) {
    sentinel_kernel<<<1, 64, 0, stream>>>((float*)d_out, (float)(ws_size >> 20));
    return;
  }

  // ---- workspace layout: ALL OFFSETS/SIZES IN BYTES (total 62,472,192) ----
  char* ws = (char*)d_ws;
  float* lse = (float*)(ws + 0);              // 6,400 B (zeroed)
  float* attnum = (float*)(ws + 8192);        // 131,072 B (zeroed)
  float* attden = (float*)(ws + 139264);      // 128 B (zeroed)
  float* tlog = (float*)(ws + 139776);        // 6,400 B
  u16* pctx = (u16*)(ws + 147456);            // 6400*1024 bf16 = 13,107,200 B
  u16* ctxb = (u16*)(ws + 13254656);          // 13,107,200 B
  u16* Wcb = (u16*)(ws + 26361856);           // 2,097,152 B
  u16* yembb = (u16*)(ws + 28459008);         // 1,638,400 B (prologue only)
  float* qpart = (float*)(ws + 28459008);     // 1,048,576 B — reuses yembb slot
  u16* Wihb = (u16*)(ws + 30097408);          // 2,097,152 B
  u16* Whhb = (u16*)(ws + 32194560);          // 2,097,152 B
  u16* Wcombb = (u16*)(ws + 34291712);        // 2,097,152 B
  u16* Uxb = (u16*)(ws + 36388864);           // 2,097,152 B
  u16* Wxb = (u16*)(ws + 38486016);           // 4,194,304 B
  float* xW = (float*)(ws + 42680320);        // 1600*2048 f32 = 13,107,200 B
  u16* feat = (u16*)(ws + 55787520);          // 1600*2048 bf16 = 6,553,600 B
  float* hbuf = (float*)(ws + 62341120);      // 32,768 B
  float* cbuf = (float*)(ws + 62373888);      // 32,768 B
  float* h1buf = (float*)(ws + 62406656);     // 32,768 B
  float* c1buf = (float*)(ws + 62439424);     // 32,768 B -> end 62,472,192

  hipMemsetAsync(ws, 0, 139776, stream);  // lse + attnum[2] + attden[2]

  CastArgs ca;
  ca.src[0] = context;  ca.dst[0] = ctxb;
  ca.src[1] = Wc_att;   ca.dst[1] = Wcb;
  ca.src[2] = y_emb;    ca.dst[2] = yembb;
  ca.src[3] = W_ih;     ca.dst[3] = Wihb;
  ca.src[4] = W_hh;     ca.dst[4] = Whhb;
  ca.src[5] = W_comb;   ca.dst[5] = Wcombb;
  ca.src[6] = Ux;       ca.dst[6] = Uxb;
  ca.src[7] = Wx;       ca.dst[7] = Wxb;
  ca.src[8] = y_emb;    ca.dst[8] = feat;
  u32 sz[9] = {819200, 131072, 102400, 131072, 131072, 131072, 131072, 262144, 102400};
  ca.cum[0] = 0;
  for (int i = 0; i < 9; i++) ca.cum[i + 1] = ca.cum[i] + sz[i];
  cast_all<<<(ca.cum[9] + 255) / 256, 256, 0, stream>>>(ca);

  // pctx = context @ Wc_att^T + b_att   [6400,1024]
  gemm_bf16<0><<<1600, 256, 0, stream>>>(ctxb, Wcb, pctx, b_att, b_att, 6400, 1024, 1024);
  // xW = y_emb @ W_ih^T + b_ih + b_hh   [1600,2048]
  gemm_bf16<1><<<800, 256, 0, stream>>>(yembb, Wihb, xW, b_ih, b_hh, 1600, 2048, 512);

  hipMemcpyAsync(hbuf, init_h, 32768, hipMemcpyDeviceToDevice, stream);
  hipMemcpyAsync(cbuf, init_c, 32768, hipMemcpyDeviceToDevice, stream);

  for (int ts = 0; ts < T_LEN; ts++) {
    int par = ts & 1;
    k1q_lstm<<<16, 256, 0, stream>>>(Whhb, Wcombb, xW, y_mask, hbuf, cbuf, h1buf, c1buf,
                                     qpart, ts);
    k3_attn<<<128, 256, 0, stream>>>(pctx, ctxb, qpart, x_mask, U_att, attnum, attden, par);
    k4_gate2<<<32, 256, 0, stream>>>(Uxb, Wxb, bx, attnum, attden, h1buf, c1buf, y_mask,
                                     hbuf, cbuf, feat, ts, par);
  }

  hipFuncSetAttribute(reinterpret_cast<const void*>(lse_gemm),
                      hipFuncAttributeMaxDynamicSharedMemorySize, 131584);
  lse_gemm<<<1563, 512, 131584, stream>>>(feat, Wp, bp, lse);

  target_logit<<<400, 256, 0, stream>>>(feat, Wp, bp, y_idx, tlog);
  finalize<<<1, 64, 0, stream>>>(lse, tlog, y_mask, (float*)d_out);
}

// Round 7
// 5534.700 us; speedup vs baseline: 1.1956x; 1.1956x over previous
//
#include <hip/hip_runtime.h>
#include <stdint.h>

typedef unsigned int u32;
typedef unsigned short u16;
typedef unsigned char u8;
typedef long long i64;
typedef __attribute__((ext_vector_type(4))) float f32x4;
typedef __attribute__((ext_vector_type(4))) float f32x4v;
typedef __attribute__((ext_vector_type(8))) short bf16x8;

#define T_LEN 100
#define S_LEN 400
#define NB 16
#define HD 512
#define CTXD 1024
#define VOC 50000
#define K4H 2048
#define M_ALL 1600

static __device__ __forceinline__ float bf2f(u16 v) {
  union { u32 u; float f; } c; c.u = ((u32)v) << 16; return c.f;
}
static __device__ __forceinline__ u16 f2bf(float f) {
  union { float f; u32 u; } c; c.f = f;
  return (u16)((c.u + 0x7fffu + ((c.u >> 16) & 1u)) >> 16);
}
static __device__ __forceinline__ u32 pack2(float a, float b) {
  return (u32)f2bf(a) | ((u32)f2bf(b) << 16);
}
static __device__ __forceinline__ uint4 pack8(float4 a, float4 b) {
  return make_uint4(pack2(a.x, a.y), pack2(a.z, a.w), pack2(b.x, b.y), pack2(b.z, b.w));
}
static __device__ __forceinline__ uint4 pack8v(f32x4v a, f32x4v b) {
  return make_uint4(pack2(a.x, a.y), pack2(a.z, a.w), pack2(b.x, b.y), pack2(b.z, b.w));
}
// pack 4 floats -> 4 fp8 e4m3 bytes (OCP)
static __device__ __forceinline__ u32 pkfp8(float x, float y, float z, float w) {
  int p = 0;
  p = __builtin_amdgcn_cvt_pk_fp8_f32(x, y, p, 0);
  p = __builtin_amdgcn_cvt_pk_fp8_f32(z, w, p, 1);
  return (u32)p;
}
static __device__ __forceinline__ float sigm(float x) { return 1.f / (1.f + __expf(-x)); }
static __device__ __forceinline__ float tanh_(float x) {
  float e = __expf(2.f * x);
  return 1.f - 2.f / (e + 1.f);
}

__global__ void sentinel_kernel(float* out, float v) {
  if (threadIdx.x < NB) out[threadIdx.x] = v;
}

// ---------------- fused cast kernel: 8 f32->bf16 segments + y_emb->fp8 feat ----------------
struct CastArgs {
  const float* src[9];
  u16* dst[9];
  u32 cum[10];  // cumulative n8 (groups of 8 elements)
};

__global__ __launch_bounds__(256) void cast_all(CastArgs A) {
  u32 i = blockIdx.x * 256 + threadIdx.x;
  if (i >= A.cum[9]) return;
  int seg = 0;
  while (i >= A.cum[seg + 1]) seg++;
  u32 li = i - A.cum[seg];
  const float* s = A.src[seg];
  f32x4v a = __builtin_nontemporal_load((const f32x4v*)&s[li * 8]);
  f32x4v b = __builtin_nontemporal_load((const f32x4v*)&s[li * 8 + 4]);
  if (seg < 8) {
    *(uint4*)&A.dst[seg][li * 8] = pack8v(a, b);
  } else {  // y_emb -> feat8[:, 1536:2048] (fp8)
    u32 m = li >> 6, k8 = (li & 63) << 3;
    u8* f8 = (u8*)A.dst[8];
    uint2 t;
    t.x = pkfp8(a.x, a.y, a.z, a.w);
    t.y = pkfp8(b.x, b.y, b.z, b.w);
    *(uint2*)&f8[(size_t)m * K4H + 1536 + k8] = t;
  }
}

// ---------------- generic bf16 MFMA GEMM: C[M,N] = A[M,K] * B[N,K]^T + bias ----------------
template <int MODE>
__global__ __launch_bounds__(256) void gemm_bf16(const u16* __restrict__ A,
                                                 const u16* __restrict__ Bw,
                                                 void* __restrict__ out,
                                                 const float* __restrict__ bias1,
                                                 const float* __restrict__ bias2,
                                                 int M, int N, int K) {
  __shared__ u16 As[64][40];
  __shared__ u16 Bs[64][40];
  int nb = N / 64;
  int m0 = (blockIdx.x / nb) * 64;
  int n0 = (blockIdx.x % nb) * 64;
  int tid = threadIdx.x;
  int lane = tid & 63;
  int w = tid >> 6;
  int wm = (w >> 1) * 32, wn = (w & 1) * 32;
  f32x4 acc[2][2] = {};
  int arow = tid >> 2, achk = (tid & 3) * 8;
  for (int k0 = 0; k0 < K; k0 += 32) {
    __syncthreads();
    *(uint4*)&As[arow][achk] = *(const uint4*)&A[(size_t)(m0 + arow) * K + k0 + achk];
    *(uint4*)&Bs[arow][achk] = *(const uint4*)&Bw[(size_t)(n0 + arow) * K + k0 + achk];
    __syncthreads();
    int r = lane & 15, kg = lane >> 4;
    bf16x8 a0 = *(const bf16x8*)&As[wm + r][kg * 8];
    bf16x8 a1 = *(const bf16x8*)&As[wm + 16 + r][kg * 8];
    bf16x8 b0 = *(const bf16x8*)&Bs[wn + r][kg * 8];
    bf16x8 b1 = *(const bf16x8*)&Bs[wn + 16 + r][kg * 8];
    acc[0][0] = __builtin_amdgcn_mfma_f32_16x16x32_bf16(a0, b0, acc[0][0], 0, 0, 0);
    acc[0][1] = __builtin_amdgcn_mfma_f32_16x16x32_bf16(a0, b1, acc[0][1], 0, 0, 0);
    acc[1][0] = __builtin_amdgcn_mfma_f32_16x16x32_bf16(a1, b0, acc[1][0], 0, 0, 0);
    acc[1][1] = __builtin_amdgcn_mfma_f32_16x16x32_bf16(a1, b1, acc[1][1], 0, 0, 0);
  }
  int col = lane & 15, rg = lane >> 4;
#pragma unroll
  for (int fi = 0; fi < 2; fi++)
#pragma unroll
    for (int fj = 0; fj < 2; fj++)
#pragma unroll
      for (int r = 0; r < 4; r++) {
        int m = m0 + wm + fi * 16 + rg * 4 + r;
        int n = n0 + wn + fj * 16 + col;
        float v = acc[fi][fj][r] + bias1[n];
        if constexpr (MODE == 1) {
          v += bias2[n];
          ((float*)out)[(size_t)m * N + n] = v;
        } else {
          ((u16*)out)[(size_t)m * N + n] = f2bf(v);
        }
      }
}

// ============ per-step kernels (3 launches per step; stream order = sync) ============

// K1Q: LSTM1 + q-partials. grid 16 blocks (j-slice of 32), 256 thr.
__global__ __launch_bounds__(256) void k1q_lstm(const u16* __restrict__ Whh,
                                                const u16* __restrict__ Wcomb,
                                                const float* __restrict__ xW,
                                                const float* __restrict__ ym,
                                                const float* __restrict__ h,
                                                const float* __restrict__ c,
                                                float* __restrict__ h1,
                                                float* __restrict__ c1,
                                                float* __restrict__ qpart, int ts) {
  __shared__ u16 Al[16 * 520];
  __shared__ float gb[4][16][32];
  __shared__ u16 h1c1[16 * 72];
  const int tid = threadIdx.x;
#pragma unroll
  for (int i = 0; i < 4; i++) {
    int idx = i * 256 + tid;
    int b = idx >> 6, k8 = (idx & 63) << 3;
    float4 a = *(const float4*)&h[b * 512 + k8];
    float4 bv = *(const float4*)&h[b * 512 + k8 + 4];
    *(uint4*)&Al[b * 520 + k8] = pack8(a, bv);
  }
  __syncthreads();
  const int lane = tid & 63, w = tid >> 6;  // w = gate in phase 1
  const int r16 = lane & 15, kg = lane >> 4;
  const int j0 = blockIdx.x * 32;
  {
    f32x4 acc0 = {}, acc1 = {};
    const size_t row0 = (size_t)(w * 512 + j0 + r16) * 512;
    const size_t row1 = (size_t)(w * 512 + j0 + 16 + r16) * 512;
#pragma unroll
    for (int ks = 0; ks < 16; ks++) {
      bf16x8 a = *(const bf16x8*)&Al[r16 * 520 + ks * 32 + kg * 8];
      bf16x8 b0 = *(const bf16x8*)&Whh[row0 + ks * 32 + kg * 8];
      bf16x8 b1 = *(const bf16x8*)&Whh[row1 + ks * 32 + kg * 8];
      acc0 = __builtin_amdgcn_mfma_f32_16x16x32_bf16(a, b0, acc0, 0, 0, 0);
      acc1 = __builtin_amdgcn_mfma_f32_16x16x32_bf16(a, b1, acc1, 0, 0, 0);
    }
#pragma unroll
    for (int r = 0; r < 4; r++) {
      gb[w][kg * 4 + r][r16] = acc0[r];
      gb[w][kg * 4 + r][16 + r16] = acc1[r];
    }
  }
  __syncthreads();
#pragma unroll
  for (int i = 0; i < 2; i++) {
    int idx = i * 256 + tid;
    int b = idx >> 5, j = idx & 31;
    int n = j0 + j;
    const float* xw = &xW[(size_t)(ts * NB + b) * K4H];
    float gi = gb[0][b][j] + xw[n];
    float gf = gb[1][b][j] + xw[512 + n];
    float gg = gb[2][b][j] + xw[1024 + n];
    float go = gb[3][b][j] + xw[1536 + n];
    float ymv = ym[ts * NB + b];
    float c_old = c[b * 512 + n], h_old = h[b * 512 + n];
    float c1v = sigm(gf) * c_old + sigm(gi) * tanh_(gg);
    float h1v = sigm(go) * tanh_(c1v);
    h1v = ymv * h1v + (1.f - ymv) * h_old;
    c1v = ymv * c1v + (1.f - ymv) * c_old;
    h1[b * 512 + n] = h1v;
    c1[b * 512 + n] = c1v;
    h1c1[b * 72 + j] = f2bf(h1v);
    h1c1[b * 72 + 32 + j] = f2bf(c1v);
  }
  __syncthreads();
  // phase 2: qpart[blk][b][n]
  {
    bf16x8 a0 = *(const bf16x8*)&h1c1[r16 * 72 + kg * 8];
    bf16x8 a1 = *(const bf16x8*)&h1c1[r16 * 72 + 32 + kg * 8];
    float* qp = qpart + blockIdx.x * 16384;
    for (int nt = w; nt < 64; nt += 4) {
      int n = nt * 16 + r16;
      bf16x8 b0 = *(const bf16x8*)&Wcomb[(size_t)n * 1024 + j0 + kg * 8];
      bf16x8 b1 = *(const bf16x8*)&Wcomb[(size_t)n * 1024 + 512 + j0 + kg * 8];
      f32x4 acc = {};
      acc = __builtin_amdgcn_mfma_f32_16x16x32_bf16(a0, b0, acc, 0, 0, 0);
      acc = __builtin_amdgcn_mfma_f32_16x16x32_bf16(a1, b1, acc, 0, 0, 0);
#pragma unroll
      for (int r = 0; r < 4; r++) qp[(kg * 4 + r) * 1024 + nt * 16 + r16] = acc[r];
    }
  }
}

// K3: attention. grid 128 = 8 s-ranges x 16 batches, 256 thr.
__global__ __launch_bounds__(256) void k3_attn(const u16* __restrict__ pctx,
                                               const u16* __restrict__ ctxb,
                                               const float* __restrict__ qpart,
                                               const float* __restrict__ xmask,
                                               const float* __restrict__ uatt,
                                               float* __restrict__ attnum,
                                               float* __restrict__ attden, int par) {
  __shared__ float q_l[1024], ua_l[1024], p_l[56], xm_l[56];
  const int tid = threadIdx.x;
  const int b = blockIdx.x & 15;
  const int s0 = (blockIdx.x >> 4) * 50;
  {
    float4 qs = {0.f, 0.f, 0.f, 0.f};
#pragma unroll
    for (int s_ = 0; s_ < 16; s_++) {
      float4 v = *(const float4*)&qpart[s_ * 16384 + b * 1024 + tid * 4];
      qs.x += v.x; qs.y += v.y; qs.z += v.z; qs.w += v.w;
    }
    *(float4*)&q_l[tid * 4] = qs;
  }
  *(float4*)&ua_l[tid * 4] = *(const float4*)&uatt[tid * 4];
  if (tid < 50) xm_l[tid] = xmask[(s0 + tid) * NB + b];
  __syncthreads();
  const int w = tid >> 6, lane = tid & 63;
  for (int i = w; i < 50; i += 4) {
    const u16* prow = &pctx[((size_t)(s0 + i) * NB + b) * CTXD + lane * 16];
    float s = 0.f;
#pragma unroll
    for (int half = 0; half < 2; half++) {
      bf16x8 pv = *(const bf16x8*)&prow[half * 8];
#pragma unroll
      for (int e = 0; e < 8; e++) {
        int cc = lane * 16 + half * 8 + e;
        s += tanh_(bf2f((u16)pv[e]) + q_l[cc]) * ua_l[cc];
      }
    }
#pragma unroll
    for (int off = 1; off < 64; off <<= 1) s += __shfl_xor(s, off);
    if (lane == 0) {
      float xm = xm_l[i];
      p_l[i] = __expf(s * xm) * xm;
    }
  }
  __syncthreads();
  const int c4 = tid << 2;
  float n0 = 0, n1 = 0, n2 = 0, n3 = 0;
  for (int i = 0; i < 50; i++) {
    float pv = p_l[i];
    uint2 ld = *(const uint2*)&ctxb[((size_t)(s0 + i) * NB + b) * CTXD + c4];
    n0 += pv * bf2f((u16)(ld.x & 0xffff));
    n1 += pv * bf2f((u16)(ld.x >> 16));
    n2 += pv * bf2f((u16)(ld.y & 0xffff));
    n3 += pv * bf2f((u16)(ld.y >> 16));
  }
  float* dst = &attnum[par * 16384 + b * 1024 + c4];
  atomicAdd(dst + 0, n0);
  atomicAdd(dst + 1, n1);
  atomicAdd(dst + 2, n2);
  atomicAdd(dst + 3, n3);
  if (tid == 0) {
    float d = 0.f;
    for (int i = 0; i < 50; i++) d += p_l[i];
    atomicAdd(&attden[par * NB + b], d);
  }
}

// K4: gates2 + h2/c2 + feat8 writes + zero other-parity att slot. grid 32, 256 thr.
__global__ __launch_bounds__(256) void k4_gate2(const u16* __restrict__ Uxw,
                                                const u16* __restrict__ Wxw,
                                                const float* __restrict__ bx,
                                                float* __restrict__ attnum,
                                                float* __restrict__ attden,
                                                const float* __restrict__ h1,
                                                const float* __restrict__ c1,
                                                const float* __restrict__ ym,
                                                float* __restrict__ h,
                                                float* __restrict__ c,
                                                u8* __restrict__ feat8, int ts, int par) {
  __shared__ u16 Al[16 * 1544];
  __shared__ float gb[4][16][16];
  const int tid = threadIdx.x;
#pragma unroll
  for (int i = 0; i < 4; i++) {
    int idx = i * 256 + tid;
    int b = idx >> 6, k8 = (idx & 63) << 3;
    float4 a = *(const float4*)&h1[b * 512 + k8];
    float4 bv = *(const float4*)&h1[b * 512 + k8 + 4];
    *(uint4*)&Al[b * 1544 + k8] = pack8(a, bv);
  }
#pragma unroll
  for (int i = 0; i < 8; i++) {
    int idx = i * 256 + tid;
    int b = idx >> 7, c8 = (idx & 127) << 3;
    float rd = 1.f / attden[par * NB + b];
    const float* src = &attnum[par * 16384 + b * 1024 + c8];
    float4 a = *(const float4*)&src[0];
    float4 bv = *(const float4*)&src[4];
    a.x *= rd; a.y *= rd; a.z *= rd; a.w *= rd;
    bv.x *= rd; bv.y *= rd; bv.z *= rd; bv.w *= rd;
    *(uint4*)&Al[b * 1544 + 512 + c8] = pack8(a, bv);
  }
  __syncthreads();
  // att -> feat8 (fp8), blocks 0..15 handle batch = blockIdx.x
  if (blockIdx.x < 16) {
    const u16* arow = &Al[blockIdx.x * 1544 + 512];
    int c4 = tid * 4;
    u32 p = pkfp8(bf2f(arow[c4]), bf2f(arow[c4 + 1]), bf2f(arow[c4 + 2]), bf2f(arow[c4 + 3]));
    *(u32*)&feat8[(size_t)(ts * NB + blockIdx.x) * K4H + 512 + c4] = p;
  }
  const int lane = tid & 63, w = tid >> 6;  // w = gate (order i,f,o,c)
  const int r16 = lane & 15, kg = lane >> 4;
  const int j0 = blockIdx.x * 16;
  f32x4 acc = {};
  const size_t rowU = (size_t)(w * 512 + j0 + r16) * 512;
  const size_t rowW = (size_t)(w * 512 + j0 + r16) * 1024;
#pragma unroll
  for (int ks = 0; ks < 16; ks++) {
    bf16x8 a = *(const bf16x8*)&Al[r16 * 1544 + ks * 32 + kg * 8];
    bf16x8 b0 = *(const bf16x8*)&Uxw[rowU + ks * 32 + kg * 8];
    acc = __builtin_amdgcn_mfma_f32_16x16x32_bf16(a, b0, acc, 0, 0, 0);
  }
#pragma unroll
  for (int ks = 16; ks < 48; ks++) {
    bf16x8 a = *(const bf16x8*)&Al[r16 * 1544 + ks * 32 + kg * 8];
    bf16x8 b0 = *(const bf16x8*)&Wxw[rowW + (ks - 16) * 32 + kg * 8];
    acc = __builtin_amdgcn_mfma_f32_16x16x32_bf16(a, b0, acc, 0, 0, 0);
  }
#pragma unroll
  for (int r = 0; r < 4; r++) gb[w][kg * 4 + r][r16] = acc[r];
  __syncthreads();
  {
    int b = tid >> 4, j = tid & 15;
    int n = j0 + j;
    float xi = gb[0][b][j] + bx[n];
    float xf = gb[1][b][j] + bx[512 + n];
    float xo = gb[2][b][j] + bx[1024 + n];
    float xc = gb[3][b][j] + bx[1536 + n];
    float ymv = ym[ts * NB + b];
    float c1v = c1[b * 512 + n], h1v = h1[b * 512 + n];
    float c2 = sigm(xf) * c1v + sigm(xi) * tanh_(xc);
    float h2 = sigm(xo) * tanh_(c2);
    c2 = ymv * c2 + (1.f - ymv) * c1v;
    h2 = ymv * h2 + (1.f - ymv) * h1v;
    h[b * 512 + n] = h2;
    c[b * 512 + n] = c2;
    int p8 = 0;
    p8 = __builtin_amdgcn_cvt_pk_fp8_f32(h2, h2, p8, 0);
    feat8[(size_t)(ts * NB + b) * K4H + n] = (u8)(p8 & 0xff);
  }
  attnum[(par ^ 1) * 16384 + blockIdx.x * 512 + tid] = 0.f;
  attnum[(par ^ 1) * 16384 + blockIdx.x * 512 + 256 + tid] = 0.f;
  if (blockIdx.x == 0 && tid < NB) attden[(par ^ 1) * NB + tid] = 0.f;
}

// ---------------- fused vocab GEMM (fp8) + sum(exp) ----------------
// 782 blocks x 64 vocab rows; LDS [64][2064 B] fp8; 512 thr (8 waves).
__global__ __launch_bounds__(512, 1) void lse_gemm_fp8(const u8* __restrict__ feat8,
                                                       const float* __restrict__ Wp,
                                                       const float* __restrict__ bp,
                                                       float* __restrict__ lse) {
  extern __shared__ char smem[];
  u8* Bl = (u8*)smem;  // [64][2064] fp8
  const int tid = threadIdx.x;
  const int n0 = blockIdx.x * 64;
  for (int n = 0; n < 64; n++) {
    int gn = n0 + n;
    f32x4v f = {0.f, 0.f, 0.f, 0.f};
    if (gn < VOC)
      f = __builtin_nontemporal_load((const f32x4v*)&Wp[(size_t)gn * K4H + tid * 4]);
    *(u32*)&Bl[n * 2064 + tid * 4] = pkfp8(f.x, f.y, f.z, f.w);
  }
  __syncthreads();
  const int w = tid >> 6, lane = tid & 63;
  const int r16 = lane & 15, kg = lane >> 4;
  bool vj[4];
  float bpj[4];
#pragma unroll
  for (int j = 0; j < 4; j++) {
    int nf = n0 + j * 16 + r16;
    vj[j] = nf < VOC;
    bpj[j] = vj[j] ? bp[nf] : 0.f;
  }
  for (int qq = w; qq < 25; qq += 8) {
    int mrow = qq * 64;
    f32x4 acc[4][4] = {};
    for (int ks = 0; ks < 64; ks++) {
      i64 b0 = *(const i64*)&Bl[(r16) * 2064 + ks * 32 + kg * 8];
      i64 b1 = *(const i64*)&Bl[(16 + r16) * 2064 + ks * 32 + kg * 8];
      i64 b2 = *(const i64*)&Bl[(32 + r16) * 2064 + ks * 32 + kg * 8];
      i64 b3 = *(const i64*)&Bl[(48 + r16) * 2064 + ks * 32 + kg * 8];
#pragma unroll
      for (int s = 0; s < 4; s++) {
        i64 a = *(const i64*)&feat8[(size_t)(mrow + s * 16 + r16) * K4H + ks * 32 + kg * 8];
        acc[s][0] = __builtin_amdgcn_mfma_f32_16x16x32_fp8_fp8(a, b0, acc[s][0], 0, 0, 0);
        acc[s][1] = __builtin_amdgcn_mfma_f32_16x16x32_fp8_fp8(a, b1, acc[s][1], 0, 0, 0);
        acc[s][2] = __builtin_amdgcn_mfma_f32_16x16x32_fp8_fp8(a, b2, acc[s][2], 0, 0, 0);
        acc[s][3] = __builtin_amdgcn_mfma_f32_16x16x32_fp8_fp8(a, b3, acc[s][3], 0, 0, 0);
      }
    }
#pragma unroll
    for (int s = 0; s < 4; s++) {
#pragma unroll
      for (int r = 0; r < 4; r++) {
        float e = 0.f;
#pragma unroll
        for (int j = 0; j < 4; j++)
          if (vj[j]) e += __expf(acc[s][j][r] + bpj[j]);
        e += __shfl_xor(e, 1);
        e += __shfl_xor(e, 2);
        e += __shfl_xor(e, 4);
        e += __shfl_xor(e, 8);
        if (r16 == 0) atomicAdd(&lse[mrow + s * 16 + kg * 4 + r], e);
      }
    }
  }
}

// ---------------- target logit (fp8 feat x f32 Wp row) ----------------
__global__ __launch_bounds__(256) void target_logit(const u8* __restrict__ feat8,
                                                    const float* __restrict__ Wp,
                                                    const float* __restrict__ bp,
                                                    const int* __restrict__ yidx,
                                                    float* __restrict__ tlog) {
  int gw = (blockIdx.x * 256 + threadIdx.x) >> 6;
  int lane = threadIdx.x & 63;
  if (gw >= M_ALL) return;
  int yi = yidx[gw];
  const float* wrow = Wp + (size_t)yi * K4H;
  const u8* frow = feat8 + (size_t)gw * K4H;
  float s = 0.f;
#pragma unroll
  for (int i = 0; i < 4; i++) {
    int k = i * 512 + lane * 8;
    uint2 fv = *(const uint2*)&frow[k];
    f32x4v w0 = __builtin_nontemporal_load((const f32x4v*)&wrow[k]);
    f32x4v w1 = __builtin_nontemporal_load((const f32x4v*)&wrow[k + 4]);
    s += __builtin_amdgcn_cvt_f32_fp8(fv.x, 0) * w0.x;
    s += __builtin_amdgcn_cvt_f32_fp8(fv.x, 1) * w0.y;
    s += __builtin_amdgcn_cvt_f32_fp8(fv.x, 2) * w0.z;
    s += __builtin_amdgcn_cvt_f32_fp8(fv.x, 3) * w0.w;
    s += __builtin_amdgcn_cvt_f32_fp8(fv.y, 0) * w1.x;
    s += __builtin_amdgcn_cvt_f32_fp8(fv.y, 1) * w1.y;
    s += __builtin_amdgcn_cvt_f32_fp8(fv.y, 2) * w1.z;
    s += __builtin_amdgcn_cvt_f32_fp8(fv.y, 3) * w1.w;
  }
#pragma unroll
  for (int off = 1; off < 64; off <<= 1) s += __shfl_xor(s, off);
  if (lane == 0) tlog[gw] = s + bp[yi];
}

__global__ void finalize(const float* __restrict__ lse, const float* __restrict__ tlog,
                         const float* __restrict__ ymask, float* __restrict__ out) {
  int b = threadIdx.x;
  if (b < NB) {
    float sc = 0.f, sm = 0.f;
    for (int t = 0; t < T_LEN; t++) {
      int m = t * NB + b;
      float ym = ymask[m];
      sc += (logf(lse[m]) - tlog[m]) * ym;
      sm += ym;
    }
    out[b] = sc / sm;
  }
}

// ---------------- host launcher ----------------
extern "C" void kernel_launch(void* const* d_in, const int* in_sizes, int n_in,
                              void* d_out, int out_size, void* d_ws, size_t ws_size,
                              hipStream_t stream) {
  const float* y_emb = (const float*)d_in[0];
  const float* context = (const float*)d_in[1];
  const float* init_h = (const float*)d_in[2];
  const float* init_c = (const float*)d_in[3];
  const float* x_mask = (const float*)d_in[4];
  const float* y_mask = (const float*)d_in[5];
  const int* y_idx = (const int*)d_in[6];
  const float* W_ih = (const float*)d_in[7];
  const float* W_hh = (const float*)d_in[8];
  const float* b_ih = (const float*)d_in[9];
  const float* b_hh = (const float*)d_in[10];
  const float* Wx = (const float*)d_in[11];
  const float* Ux = (const float*)d_in[12];
  const float* bx = (const float*)d_in[13];
  const float* Wc_att = (const float*)d_in[14];
  const float* b_att = (const float*)d_in[15];
  const float* W_comb = (const float*)d_in[16];
  const float* U_att = (const float*)d_in[17];
  const float* Wp = (const float*)d_in[18];
  const float* bp = (const float*)d_in[19];

  if (ws_size < 63000000ULL) {
    sentinel_kernel<<<1, 64, 0, stream>>>((float*)d_out, (float)(ws_size >> 20));
    return;
  }

  // ---- workspace layout: ALL OFFSETS/SIZES IN BYTES ----
  char* ws = (char*)d_ws;
  float* lse = (float*)(ws + 0);              // 6,400 B (zeroed)
  float* attnum = (float*)(ws + 8192);        // 131,072 B (zeroed)
  float* attden = (float*)(ws + 139264);      // 128 B (zeroed)
  float* tlog = (float*)(ws + 139776);        // 6,400 B
  u16* pctx = (u16*)(ws + 147456);            // 13,107,200 B
  u16* ctxb = (u16*)(ws + 13254656);          // 13,107,200 B
  u16* Wcb = (u16*)(ws + 26361856);           // 2,097,152 B
  u16* yembb = (u16*)(ws + 28459008);         // 1,638,400 B (prologue only)
  float* qpart = (float*)(ws + 28459008);     // 1,048,576 B — reuses yembb slot
  u16* Wihb = (u16*)(ws + 30097408);          // 2,097,152 B
  u16* Whhb = (u16*)(ws + 32194560);          // 2,097,152 B
  u16* Wcombb = (u16*)(ws + 34291712);        // 2,097,152 B
  u16* Uxb = (u16*)(ws + 36388864);           // 2,097,152 B
  u16* Wxb = (u16*)(ws + 38486016);           // 4,194,304 B
  float* xW = (float*)(ws + 42680320);        // 13,107,200 B
  u8* feat8 = (u8*)(ws + 55787520);           // 1600*2048 fp8 = 3,276,800 B
  float* hbuf = (float*)(ws + 62341120);      // 32,768 B
  float* cbuf = (float*)(ws + 62373888);      // 32,768 B
  float* h1buf = (float*)(ws + 62406656);     // 32,768 B
  float* c1buf = (float*)(ws + 62439424);     // 32,768 B

  hipMemsetAsync(ws, 0, 139776, stream);  // lse + attnum[2] + attden[2]

  CastArgs ca;
  ca.src[0] = context;  ca.dst[0] = ctxb;
  ca.src[1] = Wc_att;   ca.dst[1] = Wcb;
  ca.src[2] = y_emb;    ca.dst[2] = yembb;
  ca.src[3] = W_ih;     ca.dst[3] = Wihb;
  ca.src[4] = W_hh;     ca.dst[4] = Whhb;
  ca.src[5] = W_comb;   ca.dst[5] = Wcombb;
  ca.src[6] = Ux;       ca.dst[6] = Uxb;
  ca.src[7] = Wx;       ca.dst[7] = Wxb;
  ca.src[8] = y_emb;    ca.dst[8] = (u16*)feat8;
  u32 sz[9] = {819200, 131072, 102400, 131072, 131072, 131072, 131072, 262144, 102400};
  ca.cum[0] = 0;
  for (int i = 0; i < 9; i++) ca.cum[i + 1] = ca.cum[i] + sz[i];
  cast_all<<<(ca.cum[9] + 255) / 256, 256, 0, stream>>>(ca);

  // pctx = context @ Wc_att^T + b_att   [6400,1024]
  gemm_bf16<0><<<1600, 256, 0, stream>>>(ctxb, Wcb, pctx, b_att, b_att, 6400, 1024, 1024);
  // xW = y_emb @ W_ih^T + b_ih + b_hh   [1600,2048]
  gemm_bf16<1><<<800, 256, 0, stream>>>(yembb, Wihb, xW, b_ih, b_hh, 1600, 2048, 512);

  for (int ts = 0; ts < T_LEN; ts++) {
    int par = ts & 1;
    const float* hsrc = (ts == 0) ? init_h : hbuf;
    const float* csrc = (ts == 0) ? init_c : cbuf;
    k1q_lstm<<<16, 256, 0, stream>>>(Whhb, Wcombb, xW, y_mask, hsrc, csrc, h1buf, c1buf,
                                     qpart, ts);
    k3_attn<<<128, 256, 0, stream>>>(pctx, ctxb, qpart, x_mask, U_att, attnum, attden, par);
    k4_gate2<<<32, 256, 0, stream>>>(Uxb, Wxb, bx, attnum, attden, h1buf, c1buf, y_mask,
                                     hbuf, cbuf, feat8, ts, par);
  }

  hipFuncSetAttribute(reinterpret_cast<const void*>(lse_gemm_fp8),
                      hipFuncAttributeMaxDynamicSharedMemorySize, 132096);
  lse_gemm_fp8<<<782, 512, 132096, stream>>>(feat8, Wp, bp, lse);

  target_logit<<<400, 256, 0, stream>>>(feat8, Wp, bp, y_idx, tlog);
  finalize<<<1, 64, 0, stream>>>(lse, tlog, y_mask, (float*)d_out);
}